// Round 3
// baseline (577.052 us; speedup 1.0000x reference)
//
#include <hip/hip_runtime.h>

// WindowAttention fused (Swin, B_=4096, N=64, C=128, H=4, d=32), fp32 I/O,
// bf16 MFMA compute. Two kernels per launch:
//   prep_kernel: packs weights (fp32 -> bf16, fragment lane order) and the
//     block-invariant rel-pos-bias (TRANSPOSED C-layout lane order, x log2e)
//     into d_ws.
//     ws layout: [0,32K) wqP | [32K,64K) wkP | [64K,96K) wvP | [96K,128K) wpP
//                [128K,192K) rpb packed f32x4
//   winattn_kernel: one block = FOUR consecutive windows (grid 1024),
//     one wave = one head. 64KB LDS -> 2 blocks/CU (stays inside the
//     per-XCD L2 working-set budget: R1 proved 3 blocks/CU thrashes L2).
// LDS map (64KB):
//   [0,16K)   x-tile (XOR-swizzled bf16)
//   [16K,32K) per-wave V^T (4KB each); reused as the shared y-tile in step 6
//   [32K,64K) per-wave Q|K (4KB each); P (8KB) overlays Q+K
// Pipeline per window (3 barriers):
//   load next x -> regs (px[8], hides HBM latency under step-1 MFMAs)
//   step1 Q^T/K^T/V (96 MFMA) ; Q/K b64 stores (wave-private)
//   sync A ; write px -> x-LDS ; V^T b64 stores (y-region now free)
//   bias(f32x4 mask + prepacked rpb) ; step2 S^T=K.Qt (+bias via MFMA C)
//   lane-local softmax (2 shfl/row-group) ; P normalized in-reg -> b64 stores
//   step5 O = P.V ; sync B ; y -> LDS ; sync C ; step7 out^T = Wp.Yt
//   -> coalesced f32x4 cached stores (NO nontemporal: R2 showed NT raises
//      latency and leaves 1.33x write amplification; cached 2-block config
//      writes exactly out-size).
// Fragment layouts (m89/m91-verified):
//   A: lane holds A[m=lane&15][k=quad*8+j]
//   B: lane holds B[k=quad*8+j][n=lane&15]   (row-frag serves as both A and B)
//   C/D: col(n)=lane&15, row(m)=quad*4+reg
// softmax in base 2; log2e folded into Q-scale, rpb, and mask-add.

typedef __bf16 bf16x8 __attribute__((ext_vector_type(8)));
typedef __bf16 bf16x4 __attribute__((ext_vector_type(4)));
typedef float f32x4 __attribute__((ext_vector_type(4)));

#define LOG2E 1.4426950408889634f
#define QSCALE (0.17677669529663687f * 1.4426950408889634f)  // d^-0.5 * log2e

// ---------------- prep kernel ----------------
__global__ __launch_bounds__(256)
void prep_kernel(const float* __restrict__ wq,
                 const float* __restrict__ wkv,
                 const float* __restrict__ wp,
                 const float* __restrict__ bt,
                 const int* __restrict__ ri,
                 char* __restrict__ ws) {
  int t = blockIdx.x * 256 + (int)threadIdx.x;  // 0..24575
  if (t < 8192) {
    // pack one 16B bf16x8 fragment chunk of one weight stream
    int s = t >> 11;            // 0=wq 1=wk 2=wv 3=wp
    int c = t & 2047;
    int lane = c & 63, kk = (c >> 6) & 3, ct = c >> 8;  // coltile 0..7
    int li = lane & 15, q4 = lane >> 4;
    int col = ct * 16 + li;
    int ko = kk * 32 + q4 * 8;
    const float* src = (s == 0) ? (wq + col * 128 + ko)
                     : (s == 1) ? (wkv + col * 128 + ko)
                     : (s == 2) ? (wkv + (col + 128) * 128 + ko)
                                : (wp + col * 128 + ko);
    bf16x8 v;
#pragma unroll
    for (int i = 0; i < 8; ++i) v[i] = (__bf16)src[i];
    *(bf16x8*)(ws + s * 32768 + c * 16) = v;
  } else {
    // rel-pos-bias, TRANSPOSED C-layout lane order (rows=K tok, cols=Q tok),
    // x log2e.  Value at Q-token qt = tj*16+li, K-token kt = ti*16+q4*4+rr.
    int c = t - 8192;  // 0..16383
    int lane = c & 63, tj = (c >> 6) & 3, ti = (c >> 8) & 3, h = (c >> 10) & 3;
    int li = lane & 15, q4 = lane >> 4;
    int qt = tj * 16 + li;
    f32x4 r;
#pragma unroll
    for (int rr = 0; rr < 4; ++rr) {
      int kt = ti * 16 + q4 * 4 + rr;
      r[rr] = LOG2E * bt[ri[qt * 64 + kt] * 4 + h];
    }
    *(f32x4*)(ws + 131072 + c * 16) = r;
  }
}

// ---------------- main kernel ----------------
// byte offsets into smem
static __device__ __forceinline__ int xaddr(int r, int c) {       // 64x128
  return (r << 8) + ((((c >> 3) ^ (r & 7)) << 4)) + ((c & 7) << 1);
}
static __device__ __forceinline__ int qaddr(int r, int c) {       // 64x32
  return (r << 6) + ((((c >> 3) ^ ((r >> 2) & 3)) << 4)) + ((c & 7) << 1);
}
static __device__ __forceinline__ int paddr(int r, int c) {       // 64x64
  return (r << 7) + ((((c >> 3) ^ (r & 7)) << 4)) + ((c & 7) << 1);
}
static __device__ __forceinline__ int vtaddr(int dd, int m) {     // 32x64 (V^T)
  return (dd << 7) + ((((m >> 3) ^ (dd & 7)) << 4)) + ((m & 7) << 1);
}

#define MFMA16(acc, afr, bfr) \
  acc = __builtin_amdgcn_mfma_f32_16x16x32_bf16(afr, bfr, acc, 0, 0, 0)

__global__ __launch_bounds__(256, 2)
void winattn_kernel(const float* __restrict__ xg,
                    const float* __restrict__ bq,
                    const float* __restrict__ bkv,
                    const float* __restrict__ bp,
                    const float* __restrict__ mask,
                    const char* __restrict__ ws,
                    float* __restrict__ out) {
  __shared__ char smem[65536];
  const int tid = (int)threadIdx.x;
  const int h = tid >> 6;          // head / wave
  const int lane = tid & 63;
  const int q4 = lane >> 4;        // quad
  const int li = lane & 15;
  const int YB = 16384;                    // y-tile base (overlays V^T region)
  const int Vb = 16384 + h * 4096;         // per-wave V^T
  const int Qb = 32768 + h * 8192;         // per-wave Q
  const int Kb = Qb + 4096;                // per-wave K
  const int Pb = Qb;                       // P overlays Q+K
  const bf16x8* __restrict__ wqP = (const bf16x8*)(ws);
  const bf16x8* __restrict__ wkP = (const bf16x8*)(ws + 32768);
  const bf16x8* __restrict__ wvP = (const bf16x8*)(ws + 65536);
  const bf16x8* __restrict__ wpP = (const bf16x8*)(ws + 98304);
  const f32x4* __restrict__ rpbP = (const f32x4*)(ws + 131072);

  const int b0 = blockIdx.x * 4;
  f32x4 px[8];

  // ---- prologue: load + stage x(b0) ----
  {
    const float* xw = xg + (size_t)b0 * 8192;
#pragma unroll
    for (int rep = 0; rep < 4; ++rep) {
      int ch = rep * 256 + tid;
      int r = ch >> 4, cc = ch & 15;
      px[2 * rep] = *(const f32x4*)(xw + r * 128 + cc * 8);
      px[2 * rep + 1] = *(const f32x4*)(xw + r * 128 + cc * 8 + 4);
    }
#pragma unroll
    for (int rep = 0; rep < 4; ++rep) {
      int ch = rep * 256 + tid;
      int r = ch >> 4, cc = ch & 15;
      bf16x8 v;
#pragma unroll
      for (int i = 0; i < 4; ++i) {
        v[i] = (__bf16)px[2 * rep][i];
        v[i + 4] = (__bf16)px[2 * rep + 1][i];
      }
      *(bf16x8*)(smem + xaddr(r, cc * 8)) = v;
    }
  }
  __syncthreads();

#pragma unroll 1
  for (int it = 0; it < 4; ++it) {
    const int b = b0 + it;

    // ---- prefetch next window's x into registers (hides under step 1) ----
    if (it < 3) {
      const float* xw = xg + (size_t)(b + 1) * 8192;
#pragma unroll
      for (int rep = 0; rep < 4; ++rep) {
        int ch = rep * 256 + tid;
        int r = ch >> 4, cc = ch & 15;
        px[2 * rep] = *(const f32x4*)(xw + r * 128 + cc * 8);
        px[2 * rep + 1] = *(const f32x4*)(xw + r * 128 + cc * 8 + 4);
      }
    }

    // ---- step 1: Q^T/K^T (operand-swapped) and V for this head ----
    f32x4 av[4][2] = {};
    {
      f32x4 aqT[2][4] = {}; f32x4 akT[2][4] = {};
#pragma unroll
      for (int kk = 0; kk < 4; ++kk) {
        bf16x8 a[4];   // x-frag: lane holds X[16nt+li][kk*32+q4*8 ..+7]
#pragma unroll
        for (int nt = 0; nt < 4; ++nt)
          a[nt] = *(const bf16x8*)(smem + xaddr(nt * 16 + li, kk * 32 + q4 * 8));
#pragma unroll
        for (int mt = 0; mt < 2; ++mt) {
          int wi = ((h * 2 + mt) * 4 + kk) * 64 + lane;  // coalesced packed frag
          bf16x8 wbq = wqP[wi];
          bf16x8 wbk = wkP[wi];
          bf16x8 wbv = wvP[wi];
#pragma unroll
          for (int nt = 0; nt < 4; ++nt) {
            MFMA16(aqT[mt][nt], wbq, a[nt]);   // Q^T = Wq . X^T (m=feat,n=tok)
            MFMA16(akT[mt][nt], wbk, a[nt]);   // K^T = Wk . X^T
            MFMA16(av[nt][mt], a[nt], wbv);    // V   = X . Wv^T (m=tok,n=feat)
          }
        }
      }
      // Q/K: C-layout rows = 4 consecutive feats -> one b64 store per tile.
      // LDS layout stays [token][feat] with qaddr; step-2 reads unchanged.
#pragma unroll
      for (int mt = 0; mt < 2; ++mt) {
        f32x4 bq4 = *(const f32x4*)(bq + h * 32 + mt * 16 + q4 * 4);
        f32x4 bk4 = *(const f32x4*)(bkv + h * 32 + mt * 16 + q4 * 4);
        int f0 = mt * 16 + q4 * 4;
#pragma unroll
        for (int nt = 0; nt < 4; ++nt) {
          bf16x4 qv, kv;
#pragma unroll
          for (int rr = 0; rr < 4; ++rr) {
            qv[rr] = (__bf16)((aqT[mt][nt][rr] + bq4[rr]) * QSCALE);
            kv[rr] = (__bf16)(akT[mt][nt][rr] + bk4[rr]);
          }
          int row = nt * 16 + li;
          *(bf16x4*)(smem + Qb + qaddr(row, f0)) = qv;
          *(bf16x4*)(smem + Kb + qaddr(row, f0)) = kv;
        }
      }
    }
    // A: all waves done reading x (and prev window's step-7 y reads are in
    // program-order past). x-region may take next window; V^T region free.
    __syncthreads();

    if (it < 3) {
#pragma unroll
      for (int rep = 0; rep < 4; ++rep) {
        int ch = rep * 256 + tid;
        int r = ch >> 4, cc = ch & 15;
        bf16x8 v;
#pragma unroll
        for (int i = 0; i < 4; ++i) {
          v[i] = (__bf16)px[2 * rep][i];
          v[i + 4] = (__bf16)px[2 * rep + 1][i];
        }
        *(bf16x8*)(smem + xaddr(r, cc * 8)) = v;
      }
    }
    // V^T (wave-private region)
#pragma unroll
    for (int tj = 0; tj < 2; ++tj) {
      float bvv = bkv[h * 32 + tj * 16 + li + 128];
      int lc = tj * 16 + li;
#pragma unroll
      for (int ti = 0; ti < 4; ++ti) {
        bf16x4 vv;
#pragma unroll
        for (int rr = 0; rr < 4; ++rr) vv[rr] = (__bf16)(av[ti][tj][rr] + bvv);
        *(bf16x4*)(smem + Vb + vtaddr(lc, ti * 16 + q4 * 4)) = vv;
      }
    }
    asm volatile("s_waitcnt lgkmcnt(0)" ::: "memory");

    // ---- bias tile (transposed): rpb (prepacked) + log2e * mask ----
    // bias[ti][tj][rr] = value at Q-token tj*16+li, K-token ti*16+q4*4+rr
    f32x4 bias[4][4];
    {
      const float* mw = mask + (size_t)b * 4096;
#pragma unroll
      for (int ti = 0; ti < 4; ++ti)
#pragma unroll
        for (int tj = 0; tj < 4; ++tj) {
          f32x4 rv = rpbP[((h * 4 + ti) * 4 + tj) * 64 + lane];
          f32x4 mv = *(const f32x4*)(mw + (tj * 16 + li) * 64 + ti * 16 + q4 * 4);
#pragma unroll
          for (int rr = 0; rr < 4; ++rr) rv[rr] = fmaf(LOG2E, mv[rr], rv[rr]);
          bias[ti][tj] = rv;
        }
    }

    // ---- step 2: S^T = K Q^T (+bias^T via MFMA C) ----
    f32x4 S[4][4];
    {
      bf16x8 qf[4], kf[4];
#pragma unroll
      for (int t = 0; t < 4; ++t) {
        qf[t] = *(const bf16x8*)(smem + Qb + qaddr(t * 16 + li, q4 * 8));
        kf[t] = *(const bf16x8*)(smem + Kb + qaddr(t * 16 + li, q4 * 8));
      }
#pragma unroll
      for (int ti = 0; ti < 4; ++ti)
#pragma unroll
        for (int tj = 0; tj < 4; ++tj)
          S[ti][tj] = __builtin_amdgcn_mfma_f32_16x16x32_bf16(
              kf[ti], qf[tj], bias[ti][tj], 0, 0, 0);
    }

    // ---- step 3: softmax over K = lane-local + 2 shuffles; normalize ----
#pragma unroll
    for (int tj = 0; tj < 4; ++tj) {
      float mx = S[0][tj][0];
#pragma unroll
      for (int ti = 0; ti < 4; ++ti)
#pragma unroll
        for (int rr = 0; rr < 4; ++rr) mx = fmaxf(mx, S[ti][tj][rr]);
      mx = fmaxf(mx, __shfl_xor(mx, 16));
      mx = fmaxf(mx, __shfl_xor(mx, 32));
      float s = 0.f;
#pragma unroll
      for (int ti = 0; ti < 4; ++ti)
#pragma unroll
        for (int rr = 0; rr < 4; ++rr) {
          float e = __builtin_amdgcn_exp2f(S[ti][tj][rr] - mx);
          S[ti][tj][rr] = e;
          s += e;
        }
      s += __shfl_xor(s, 16);
      s += __shfl_xor(s, 32);
      float rinv = __builtin_amdgcn_rcpf(s);
#pragma unroll
      for (int ti = 0; ti < 4; ++ti)
#pragma unroll
        for (int rr = 0; rr < 4; ++rr) S[ti][tj][rr] *= rinv;
    }

    // ---- step 4: P (bf16, normalized) -> LDS b64 (overlays Q/K) ----
    // lane holds P[qt = tj*16+li][kt = ti*16+q4*4 .. +3]
#pragma unroll
    for (int ti = 0; ti < 4; ++ti)
#pragma unroll
      for (int tj = 0; tj < 4; ++tj) {
        bf16x4 pv;
#pragma unroll
        for (int rr = 0; rr < 4; ++rr) pv[rr] = (__bf16)S[ti][tj][rr];
        *(bf16x4*)(smem + Pb + paddr(tj * 16 + li, ti * 16 + q4 * 4)) = pv;
      }
    asm volatile("s_waitcnt lgkmcnt(0)" ::: "memory");

    // ---- step 5: O = P V (4x2 tiles, K=64) ----
    f32x4 O[4][2] = {};
#pragma unroll
    for (int ks = 0; ks < 2; ++ks) {
      bf16x8 pf[4], vf[2];
#pragma unroll
      for (int ti = 0; ti < 4; ++ti)
        pf[ti] = *(const bf16x8*)(smem + Pb + paddr(ti * 16 + li, ks * 32 + q4 * 8));
#pragma unroll
      for (int tj = 0; tj < 2; ++tj)
        vf[tj] = *(const bf16x8*)(smem + Vb + vtaddr(tj * 16 + li, ks * 32 + q4 * 8));
#pragma unroll
      for (int ti = 0; ti < 4; ++ti)
#pragma unroll
        for (int tj = 0; tj < 2; ++tj)
          MFMA16(O[ti][tj], pf[ti], vf[tj]);
    }

    // ---- step 6: y into the V^T region (all waves done with V reads) ----
    __syncthreads();   // B
#pragma unroll
    for (int ti = 0; ti < 4; ++ti)
#pragma unroll
      for (int tj = 0; tj < 2; ++tj)
#pragma unroll
        for (int rr = 0; rr < 4; ++rr) {
          int row = ti * 16 + q4 * 4 + rr;
          int col = h * 32 + tj * 16 + li;
          *(__bf16*)(smem + YB + xaddr(row, col)) = (__bf16)O[ti][tj][rr];
        }
    __syncthreads();   // C

    // ---- step 7: out^T = Wp . y^T -> coalesced cached f32x4 stores ----
    {
      f32x4 acc[2][4] = {};
#pragma unroll
      for (int kk = 0; kk < 4; ++kk) {
        bf16x8 a[4];   // y-frag serves as B operand (n = token)
#pragma unroll
        for (int nt = 0; nt < 4; ++nt)
          a[nt] = *(const bf16x8*)(smem + YB + xaddr(nt * 16 + li, kk * 32 + q4 * 8));
#pragma unroll
        for (int mt = 0; mt < 2; ++mt) {
          int wi = ((h * 2 + mt) * 4 + kk) * 64 + lane;
          bf16x8 wb = wpP[wi];
#pragma unroll
          for (int nt = 0; nt < 4; ++nt)
            MFMA16(acc[mt][nt], wb, a[nt]);  // rows = proj feat, cols = token
        }
      }
      float* ow = out + (size_t)b * 8192;
#pragma unroll
      for (int mt = 0; mt < 2; ++mt) {
        f32x4 bp4 = *(const f32x4*)(bp + h * 32 + mt * 16 + q4 * 4);
#pragma unroll
        for (int nt = 0; nt < 4; ++nt) {
          f32x4 o;
#pragma unroll
          for (int rr = 0; rr < 4; ++rr) o[rr] = acc[mt][nt][rr] + bp4[rr];
          *(f32x4*)(ow + (nt * 16 + li) * 128 + h * 32 + mt * 16 + q4 * 4) = o;
        }
      }
    }
  }
}

extern "C" void kernel_launch(void* const* d_in, const int* in_sizes, int n_in,
                              void* d_out, int out_size, void* d_ws, size_t ws_size,
                              hipStream_t stream) {
  (void)in_sizes; (void)n_in; (void)ws_size; (void)out_size;
  prep_kernel<<<96, 256, 0, stream>>>(
      (const float*)d_in[1],   // wq
      (const float*)d_in[3],   // wkv
      (const float*)d_in[6],   // wproj
      (const float*)d_in[5],   // bias_table
      (const int*)d_in[9],     // rel_index
      (char*)d_ws);
  winattn_kernel<<<1024, 256, 0, stream>>>(
      (const float*)d_in[0],   // x
      (const float*)d_in[2],   // bq
      (const float*)d_in[4],   // bkv
      (const float*)d_in[7],   // bproj
      (const float*)d_in[8],   // mask
      (const char*)d_ws,
      (float*)d_out);
}

// Round 5
// 326.679 us; speedup vs baseline: 1.7664x; 1.7664x over previous
//
#include <hip/hip_runtime.h>

// WindowAttention fused (Swin, B_=4096, N=64, C=128, H=4, d=32), fp32 I/O,
// bf16 MFMA compute. Two kernels per launch:
//   prep_kernel: packs weights (fp32 -> bf16, fragment lane order) and the
//     block-invariant rel-pos-bias (TRANSPOSED C-layout lane order, x log2e)
//     into d_ws.
//     ws layout: [0,32K) wqP | [32K,64K) wkP | [64K,96K) wvP | [96K,128K) wpP
//                [128K,192K) rpb packed f32x4
//   winattn_kernel: one block = one window (grid 4096), one wave = one head.
// CONFIG LESSONS (R1-R3, measured):
//   - 64KB LDS / 2 blocks/CU is the ONLY clean config: 3 blocks/CU thrashes
//     per-XCD L2 (WRITE 131->213MB, R1). Keep 64KB.
//   - Nontemporal loads/stores REGRESS (latency-bound kernel; R2).
//   - Register x-prefetch across step-1 spills to scratch (VGPR 84->128,
//     3x HBM traffic; R3). No prefetch; keep R1's proven step-1 live set.
// LDS map (64KB): [0,16K) x-tile (XOR-swizzled bf16; y overlays it at step 6)
//   [16K+h*12K): per-wave Q (4K) | K (4K) | V^T (4K); P (8K) overlays Q+K.
// Operand-swapped MFMAs keep every epilogue vectorized:
//   step 1: Q^T = Wq.Xt, K^T = Wk.Xt -> b64 stores into [token][feat]
//   step 2: S^T = K.Qt (+bias^T via C) -> softmax lane-local, P normalized
//           in-register -> 16x b64 stores
//   step 5: O^T = V^T.P^T (same LDS frags) -> step 6 y-write = 8x b64 stores
//   step 7: out^T = Wp.Yt -> 8x cached dwordx4 fp32 stores
// Mask/rpb loads issue BEFORE the lgkmcnt(0) store-drain (latency overlap).
// Fragment layouts (m89/m91-verified):
//   A: lane holds A[m=lane&15][k=quad*8+j]
//   B: lane holds B[k=quad*8+j][n=lane&15]   (row-frag serves as both A and B)
//   C/D: col(n)=lane&15, row(m)=quad*4+reg
// softmax in base 2; log2e folded into Q-scale, rpb, and mask-add.

typedef __bf16 bf16x8 __attribute__((ext_vector_type(8)));
typedef __bf16 bf16x4 __attribute__((ext_vector_type(4)));
typedef float f32x4 __attribute__((ext_vector_type(4)));

#define LOG2E 1.4426950408889634f
#define QSCALE (0.17677669529663687f * 1.4426950408889634f)  // d^-0.5 * log2e

// ---------------- prep kernel ----------------
__global__ __launch_bounds__(256)
void prep_kernel(const float* __restrict__ wq,
                 const float* __restrict__ wkv,
                 const float* __restrict__ wp,
                 const float* __restrict__ bt,
                 const int* __restrict__ ri,
                 char* __restrict__ ws) {
  int t = blockIdx.x * 256 + (int)threadIdx.x;  // 0..24575
  if (t < 8192) {
    // pack one 16B bf16x8 fragment chunk of one weight stream
    int s = t >> 11;            // 0=wq 1=wk 2=wv 3=wp
    int c = t & 2047;
    int lane = c & 63, kk = (c >> 6) & 3, ct = c >> 8;  // coltile 0..7
    int li = lane & 15, q4 = lane >> 4;
    int col = ct * 16 + li;
    int ko = kk * 32 + q4 * 8;
    const float* src = (s == 0) ? (wq + col * 128 + ko)
                     : (s == 1) ? (wkv + col * 128 + ko)
                     : (s == 2) ? (wkv + (col + 128) * 128 + ko)
                                : (wp + col * 128 + ko);
    bf16x8 v;
#pragma unroll
    for (int i = 0; i < 8; ++i) v[i] = (__bf16)src[i];
    *(bf16x8*)(ws + s * 32768 + c * 16) = v;
  } else {
    // rel-pos-bias, TRANSPOSED C-layout lane order (rows=K tok, cols=Q tok),
    // x log2e.  Value at Q-token qt = tj*16+li, K-token kt = ti*16+q4*4+rr.
    int c = t - 8192;  // 0..16383
    int lane = c & 63, tj = (c >> 6) & 3, ti = (c >> 8) & 3, h = (c >> 10) & 3;
    int li = lane & 15, q4 = lane >> 4;
    int qt = tj * 16 + li;
    f32x4 r;
#pragma unroll
    for (int rr = 0; rr < 4; ++rr) {
      int kt = ti * 16 + q4 * 4 + rr;
      r[rr] = LOG2E * bt[ri[qt * 64 + kt] * 4 + h];
    }
    *(f32x4*)(ws + 131072 + c * 16) = r;
  }
}

// ---------------- main kernel ----------------
static __device__ __forceinline__ bf16x8 cvt8(const float* __restrict__ p) {
  f32x4 a = *(const f32x4*)p;
  f32x4 b = *((const f32x4*)p + 1);
  bf16x8 r;
#pragma unroll
  for (int i = 0; i < 4; ++i) { r[i] = (__bf16)a[i]; r[i + 4] = (__bf16)b[i]; }
  return r;
}

// byte offsets into smem
static __device__ __forceinline__ int xaddr(int r, int c) {       // 64x128
  return (r << 8) + ((((c >> 3) ^ (r & 7)) << 4)) + ((c & 7) << 1);
}
static __device__ __forceinline__ int qaddr(int r, int c) {       // 64x32
  return (r << 6) + ((((c >> 3) ^ ((r >> 2) & 3)) << 4)) + ((c & 7) << 1);
}
static __device__ __forceinline__ int paddr(int r, int c) {       // 64x64
  return (r << 7) + ((((c >> 3) ^ (r & 7)) << 4)) + ((c & 7) << 1);
}
static __device__ __forceinline__ int vtaddr(int dd, int m) {     // 32x64 (V^T)
  return (dd << 7) + ((((m >> 3) ^ (dd & 7)) << 4)) + ((m & 7) << 1);
}

#define MFMA16(acc, afr, bfr) \
  acc = __builtin_amdgcn_mfma_f32_16x16x32_bf16(afr, bfr, acc, 0, 0, 0)

__global__ __launch_bounds__(256, 2)
void winattn_kernel(const float* __restrict__ xg,
                    const float* __restrict__ bq,
                    const float* __restrict__ bkv,
                    const float* __restrict__ bp,
                    const float* __restrict__ mask,
                    const char* __restrict__ ws,
                    float* __restrict__ out) {
  __shared__ char smem[65536];
  const int b = blockIdx.x;
  const int tid = (int)threadIdx.x;
  const int h = tid >> 6;          // head / wave
  const int lane = tid & 63;
  const int q4 = lane >> 4;        // quad
  const int li = lane & 15;
  const int Wb = 16384 + h * 12288;
  const int Qb = Wb, Kb = Wb + 4096, Vb = Wb + 8192, Pb = Wb;
  const bf16x8* __restrict__ wqP = (const bf16x8*)(ws);
  const bf16x8* __restrict__ wkP = (const bf16x8*)(ws + 32768);
  const bf16x8* __restrict__ wvP = (const bf16x8*)(ws + 65536);
  const bf16x8* __restrict__ wpP = (const bf16x8*)(ws + 98304);
  const f32x4* __restrict__ rpbP = (const f32x4*)(ws + 131072);

  // ---- stage x window (64x128 fp32 -> bf16 in LDS, coalesced, cached) ----
  {
    const float* xw = xg + (size_t)b * 8192;
#pragma unroll
    for (int rep = 0; rep < 4; ++rep) {
      int chunk = rep * 256 + tid;       // 1024 x 8-element chunks
      int r = chunk >> 4, cc = chunk & 15;
      bf16x8 v = cvt8(xw + r * 128 + cc * 8);
      *(bf16x8*)(smem + xaddr(r, cc * 8)) = v;
    }
  }
  __syncthreads();

  // ---- step 1: Q^T/K^T (operand-swapped) and V for this head ----
  {
    f32x4 aqT[2][4] = {}; f32x4 akT[2][4] = {}; f32x4 av[4][2] = {};
#pragma unroll
    for (int kk = 0; kk < 4; ++kk) {
      bf16x8 a[4];   // x-frag: lane holds X[16nt+li][kk*32+q4*8 ..+7]
#pragma unroll
      for (int nt = 0; nt < 4; ++nt)
        a[nt] = *(const bf16x8*)(smem + xaddr(nt * 16 + li, kk * 32 + q4 * 8));
#pragma unroll
      for (int mt = 0; mt < 2; ++mt) {
        int wi = ((h * 2 + mt) * 4 + kk) * 64 + lane;   // coalesced packed frag
        bf16x8 wbq = wqP[wi];
        bf16x8 wbk = wkP[wi];
        bf16x8 wbv = wvP[wi];
#pragma unroll
        for (int nt = 0; nt < 4; ++nt) {
          MFMA16(aqT[mt][nt], wbq, a[nt]);   // Q^T = Wq . X^T (m=feat, n=tok)
          MFMA16(akT[mt][nt], wbk, a[nt]);   // K^T = Wk . X^T
          MFMA16(av[nt][mt], a[nt], wbv);    // V   = X . Wv^T (m=tok, n=feat)
        }
      }
    }
    // Q/K: C-layout rows = 4 consecutive feats -> one b64 store per tile.
    // LDS layout stays [token][feat] with qaddr; step-2 reads unchanged.
#pragma unroll
    for (int mt = 0; mt < 2; ++mt) {
      f32x4 bq4 = *(const f32x4*)(bq + h * 32 + mt * 16 + q4 * 4);
      f32x4 bk4 = *(const f32x4*)(bkv + h * 32 + mt * 16 + q4 * 4);
      int f0 = mt * 16 + q4 * 4;
#pragma unroll
      for (int nt = 0; nt < 4; ++nt) {
        bf16x4 qv, kv;
#pragma unroll
        for (int rr = 0; rr < 4; ++rr) {
          qv[rr] = (__bf16)((aqT[mt][nt][rr] + bq4[rr]) * QSCALE);
          kv[rr] = (__bf16)(akT[mt][nt][rr] + bk4[rr]);
        }
        int row = nt * 16 + li;
        *(bf16x4*)(smem + Qb + qaddr(row, f0)) = qv;
        *(bf16x4*)(smem + Kb + qaddr(row, f0)) = kv;
      }
    }
    // V^T (wave-private region, no barrier needed)
#pragma unroll
    for (int tj = 0; tj < 2; ++tj) {
      float bvv = bkv[h * 32 + tj * 16 + li + 128];
      int lc = tj * 16 + li;
#pragma unroll
      for (int ti = 0; ti < 4; ++ti) {
        bf16x4 vv;
#pragma unroll
        for (int rr = 0; rr < 4; ++rr) vv[rr] = (__bf16)(av[ti][tj][rr] + bvv);
        *(bf16x4*)(smem + Vb + vtaddr(lc, ti * 16 + q4 * 4)) = vv;
      }
    }
  }

  // ---- bias tile (transposed): rpb (prepacked) + log2e * mask. Loads
  // issue BEFORE the store-drain wait so HBM latency overlaps it. ----
  // bias[ti][tj][rr] = value at Q-token tj*16+li, K-token ti*16+q4*4+rr
  f32x4 bias[4][4];
  {
    const float* mw = mask + (size_t)b * 4096;
#pragma unroll
    for (int ti = 0; ti < 4; ++ti)
#pragma unroll
      for (int tj = 0; tj < 4; ++tj) {
        f32x4 rv = rpbP[((h * 4 + ti) * 4 + tj) * 64 + lane];
        f32x4 mv = *(const f32x4*)(mw + (tj * 16 + li) * 64 + ti * 16 + q4 * 4);
#pragma unroll
        for (int rr = 0; rr < 4; ++rr) rv[rr] = fmaf(LOG2E, mv[rr], rv[rr]);
        bias[ti][tj] = rv;
      }
  }
  asm volatile("s_waitcnt lgkmcnt(0)" ::: "memory");

  // ---- step 2: S^T = K Q^T (+bias^T via MFMA C), rows=K tok, cols=Q tok ----
  f32x4 S[4][4];
  {
    bf16x8 qf[4], kf[4];
#pragma unroll
    for (int t = 0; t < 4; ++t) {
      qf[t] = *(const bf16x8*)(smem + Qb + qaddr(t * 16 + li, q4 * 8));
      kf[t] = *(const bf16x8*)(smem + Kb + qaddr(t * 16 + li, q4 * 8));
    }
#pragma unroll
    for (int ti = 0; ti < 4; ++ti)
#pragma unroll
      for (int tj = 0; tj < 4; ++tj)
        S[ti][tj] = __builtin_amdgcn_mfma_f32_16x16x32_bf16(
            kf[ti], qf[tj], bias[ti][tj], 0, 0, 0);
  }

  // ---- step 3: softmax over K = lane-local + 2 shuffles; normalize ----
#pragma unroll
  for (int tj = 0; tj < 4; ++tj) {
    float mx = S[0][tj][0];
#pragma unroll
    for (int ti = 0; ti < 4; ++ti)
#pragma unroll
      for (int rr = 0; rr < 4; ++rr) mx = fmaxf(mx, S[ti][tj][rr]);
    mx = fmaxf(mx, __shfl_xor(mx, 16));
    mx = fmaxf(mx, __shfl_xor(mx, 32));
    float s = 0.f;
#pragma unroll
    for (int ti = 0; ti < 4; ++ti)
#pragma unroll
      for (int rr = 0; rr < 4; ++rr) {
        float e = __builtin_amdgcn_exp2f(S[ti][tj][rr] - mx);
        S[ti][tj][rr] = e;
        s += e;
      }
    s += __shfl_xor(s, 16);
    s += __shfl_xor(s, 32);
    float rinv = __builtin_amdgcn_rcpf(s);
#pragma unroll
    for (int ti = 0; ti < 4; ++ti)
#pragma unroll
      for (int rr = 0; rr < 4; ++rr) S[ti][tj][rr] *= rinv;
  }

  // ---- step 4: P (bf16, normalized) -> LDS b64 (overlays Q/K) ----
  // lane holds P[qt = tj*16+li][kt = ti*16+q4*4 .. +3]
#pragma unroll
  for (int ti = 0; ti < 4; ++ti)
#pragma unroll
    for (int tj = 0; tj < 4; ++tj) {
      bf16x4 pv;
#pragma unroll
      for (int rr = 0; rr < 4; ++rr) pv[rr] = (__bf16)S[ti][tj][rr];
      *(bf16x4*)(smem + Pb + paddr(tj * 16 + li, ti * 16 + q4 * 4)) = pv;
    }
  asm volatile("s_waitcnt lgkmcnt(0)" ::: "memory");

  // ---- step 5: O^T = V^T . P^T (2x4 tiles, K=64; same LDS fragments:
  //      V^T-read serves as A, P-read serves as B). O^T C-layout rows =
  //      4 consecutive feats -> step-6 b64 stores. P pre-normalized. ----
  f32x4 OT[2][4] = {};
#pragma unroll
  for (int ks = 0; ks < 2; ++ks) {
    bf16x8 pf[4], vf[2];
#pragma unroll
    for (int nt = 0; nt < 4; ++nt)
      pf[nt] = *(const bf16x8*)(smem + Pb + paddr(nt * 16 + li, ks * 32 + q4 * 8));
#pragma unroll
    for (int mt = 0; mt < 2; ++mt)
      vf[mt] = *(const bf16x8*)(smem + Vb + vtaddr(mt * 16 + li, ks * 32 + q4 * 8));
#pragma unroll
    for (int mt = 0; mt < 2; ++mt)
#pragma unroll
      for (int nt = 0; nt < 4; ++nt)
        MFMA16(OT[mt][nt], vf[mt], pf[nt]);
  }

  // ---- step 6: y (64x128, [tok][feat]) into x region via b64 stores ----
  __syncthreads();   // all waves done reading x
#pragma unroll
  for (int mt = 0; mt < 2; ++mt) {
    int f0 = h * 32 + mt * 16 + q4 * 4;
#pragma unroll
    for (int nt = 0; nt < 4; ++nt) {
      bf16x4 yv;
#pragma unroll
      for (int rr = 0; rr < 4; ++rr) yv[rr] = (__bf16)OT[mt][nt][rr];
      *(bf16x4*)(smem + xaddr(nt * 16 + li, f0)) = yv;
    }
  }
  __syncthreads();

  // ---- step 7: out^T = Wp . y^T -> coalesced cached f32x4 stores ----
  {
    f32x4 acc[2][4] = {};
#pragma unroll
    for (int kk = 0; kk < 4; ++kk) {
      bf16x8 a[4];   // y-frag serves as B operand (n = token)
#pragma unroll
      for (int nt = 0; nt < 4; ++nt)
        a[nt] = *(const bf16x8*)(smem + xaddr(nt * 16 + li, kk * 32 + q4 * 8));
#pragma unroll
      for (int mt = 0; mt < 2; ++mt) {
        int wi = ((h * 2 + mt) * 4 + kk) * 64 + lane;
        bf16x8 wb = wpP[wi];
#pragma unroll
        for (int nt = 0; nt < 4; ++nt)
          MFMA16(acc[mt][nt], wb, a[nt]);    // rows = proj feat, cols = token
      }
    }
    float* ow = out + (size_t)b * 8192;
#pragma unroll
    for (int mt = 0; mt < 2; ++mt) {
      f32x4 bp4 = *(const f32x4*)(bp + h * 32 + mt * 16 + q4 * 4);
#pragma unroll
      for (int nt = 0; nt < 4; ++nt) {
        f32x4 o;
#pragma unroll
        for (int rr = 0; rr < 4; ++rr) o[rr] = acc[mt][nt][rr] + bp4[rr];
        *(f32x4*)(ow + (nt * 16 + li) * 128 + h * 32 + mt * 16 + q4 * 4) = o;
      }
    }
  }
}

extern "C" void kernel_launch(void* const* d_in, const int* in_sizes, int n_in,
                              void* d_out, int out_size, void* d_ws, size_t ws_size,
                              hipStream_t stream) {
  (void)in_sizes; (void)n_in; (void)ws_size; (void)out_size;
  prep_kernel<<<96, 256, 0, stream>>>(
      (const float*)d_in[1],   // wq
      (const float*)d_in[3],   // wkv
      (const float*)d_in[6],   // wproj
      (const float*)d_in[5],   // bias_table
      (const int*)d_in[9],     // rel_index
      (char*)d_ws);
  winattn_kernel<<<4096, 256, 0, stream>>>(
      (const float*)d_in[0],   // x
      (const float*)d_in[2],   // bq
      (const float*)d_in[4],   // bkv
      (const float*)d_in[7],   // bproj
      (const float*)d_in[8],   // mask
      (const char*)d_ws,
      (float*)d_out);
}